// Round 5
// baseline (148.428 us; speedup 1.0000x reference)
//
#include <hip/hip_runtime.h>
#include <math.h>

namespace {
constexpr int kN = 22;
constexpr int kF = 448;
constexpr int kNP = 484;

// ---- LDS float offsets (one 16192-float pool = 64768 B) ----
// Region X [0, 9944) is phase-overlaid:
//   phase1: x tile [22][452]
//   phase2 (GEMM): A_t dbuf [2][16][26] @0, W dbuf [2][16][260] @832
//   phase3: vbuf [128][68] @0, zc [128][2] @8704, consts @8960 (256)
constexpr int kXStr = 452;
constexpr int oAT   = 0;     constexpr int kATb = 416;
constexpr int oW    = 832;   constexpr int kWb  = 4160;  constexpr int kWStr = 260;
constexpr int oVB   = 0;     constexpr int kVStr = 68;
constexpr int oZC   = 8704;
constexpr int oCst  = 8960;
// persistent regions:
constexpr int oP    = 9944;  constexpr int kPStr = 260;   // proj [22][260]: a1|a2|u1|u2
constexpr int oSG   = 15664;                              // |corr| 484
constexpr int oMU   = 16148;
constexpr int oIS   = 16170;
constexpr int kSm   = 16192;

__device__ __forceinline__ void map_slot(int s, int& i, int& j) {
    // s<231: strict upper (i<j); else diagonal
    if (s < 231) {
        int rem = s, i0 = 0;
        while (rem >= 21 - i0) { rem -= 21 - i0; ++i0; }
        i = i0; j = i0 + 1 + rem;
    } else {
        i = j = s - 231;
    }
}
}

__global__ __launch_bounds__(512) void hgc_fused(
    const float* __restrict__ x,
    const float* __restrict__ cw1, const float* __restrict__ cb1,
    const float* __restrict__ cw2, const float* __restrict__ cb2,
    const float* __restrict__ emb,
    const float* __restrict__ sw1, const float* __restrict__ sb1,
    const float* __restrict__ ln_g, const float* __restrict__ ln_b,
    const float* __restrict__ sw2, const float* __restrict__ sb2,
    const float* __restrict__ sw3, const float* __restrict__ sb3,
    const float* __restrict__ thr, const float* __restrict__ alpha_p,
    float* __restrict__ out)
{
    __shared__ __align__(16) float sm[kSm];
    const int tid = threadIdx.x;
    const int b   = blockIdx.x;
    const float* xb = x + (size_t)b * (kN * kF);

    // ================= phase 1: x tile, stats, corr =================
    for (int idx = tid; idx < kN * 112; idx += 512) {
        const int r = idx / 112, q = idx - r * 112;
        *(float4*)&sm[r * kXStr + q * 4] = *(const float4*)&xb[r * kF + q * 4];
    }
    __syncthreads();
    {
        const int w = tid >> 6, l = tid & 63;
        for (int r = w; r < kN; r += 8) {
            const float* row = sm + r * kXStr;
            float s = 0.f;
            #pragma unroll
            for (int c = 0; c < 7; ++c) s += row[c * 64 + l];
            #pragma unroll
            for (int o = 32; o; o >>= 1) s += __shfl_xor(s, o, 64);
            const float mean = s * (1.f / 448.f);
            float ss = 0.f;
            #pragma unroll
            for (int c = 0; c < 7; ++c) { const float d = row[c * 64 + l] - mean; ss = fmaf(d, d, ss); }
            #pragma unroll
            for (int o = 32; o; o >>= 1) ss += __shfl_xor(ss, o, 64);
            if (l == 0) {
                sm[oMU + r] = mean;
                sm[oIS + r] = 1.f / (sqrtf(ss * (1.f / 447.f)) + 1e-8f);  // ddof=1
            }
        }
    }
    __syncthreads();
    if (tid < 264) {   // 66 2x2-pair tiles x 4 K-split lanes
        const int tile = tid >> 2, kt = tid & 3;
        int ti = 0, rem = tile;
        while (rem >= 11 - ti) { rem -= 11 - ti; ++ti; }
        const int tj = ti + rem;
        const float* xi0 = sm + (2 * ti) * kXStr;
        const float* xi1 = xi0 + kXStr;
        const float* xj0 = sm + (2 * tj) * kXStr;
        const float* xj1 = xj0 + kXStr;
        float d00 = 0.f, d01 = 0.f, d10 = 0.f, d11 = 0.f;
        for (int q = kt * 28; q < kt * 28 + 28; ++q) {
            const float4 A0 = *(const float4*)&xi0[q * 4];
            const float4 A1 = *(const float4*)&xi1[q * 4];
            const float4 B0 = *(const float4*)&xj0[q * 4];
            const float4 B1 = *(const float4*)&xj1[q * 4];
            d00 = fmaf(A0.x, B0.x, d00); d00 = fmaf(A0.y, B0.y, d00);
            d00 = fmaf(A0.z, B0.z, d00); d00 = fmaf(A0.w, B0.w, d00);
            d01 = fmaf(A0.x, B1.x, d01); d01 = fmaf(A0.y, B1.y, d01);
            d01 = fmaf(A0.z, B1.z, d01); d01 = fmaf(A0.w, B1.w, d01);
            d10 = fmaf(A1.x, B0.x, d10); d10 = fmaf(A1.y, B0.y, d10);
            d10 = fmaf(A1.z, B0.z, d10); d10 = fmaf(A1.w, B0.w, d10);
            d11 = fmaf(A1.x, B1.x, d11); d11 = fmaf(A1.y, B1.y, d11);
            d11 = fmaf(A1.z, B1.z, d11); d11 = fmaf(A1.w, B1.w, d11);
        }
        d00 += __shfl_xor(d00, 1, 64); d00 += __shfl_xor(d00, 2, 64);
        d01 += __shfl_xor(d01, 1, 64); d01 += __shfl_xor(d01, 2, 64);
        d10 += __shfl_xor(d10, 1, 64); d10 += __shfl_xor(d10, 2, 64);
        d11 += __shfl_xor(d11, 1, 64); d11 += __shfl_xor(d11, 2, 64);
        if (kt == 0) {
            const float dd[2][2] = {{d00, d01}, {d10, d11}};
            #pragma unroll
            for (int a = 0; a < 2; ++a)
                #pragma unroll
                for (int e = 0; e < 2; ++e) {
                    const int i = 2 * ti + a, j = 2 * tj + e;
                    const float c = (dd[a][e] - 448.f * sm[oMU + i] * sm[oMU + j])
                                    * sm[oIS + i] * sm[oIS + j] * (1.f / 448.f);
                    const float ac = fabsf(c);
                    sm[oSG + i * 22 + j] = ac;
                    sm[oSG + j * 22 + i] = ac;
                }
        }
    }
    __syncthreads();

    // ================= phase 2: projections GEMM =================
    // 24 rows x 256 cols; wave: g=colgroup(64 cols), h=rowhalf(12 rows)
    // lane: sgp=rowtriple, q16=col-quad. 3x4 microtile.
    const int tm = tid >> 6, lane = tid & 63;
    const int g = tm & 3, h = tm >> 2;
    const int sgp = lane >> 4, q16 = lane & 15;
    const int r0 = h * 12 + sgp * 3;
    const int col = g * 64 + q16 * 4;
    float4 acc0 = {0,0,0,0}, acc1 = {0,0,0,0}, acc2 = {0,0,0,0};
    const int am = tid >> 2, aq = tid & 3;   // A-staging role (tid<96)
    float4 pA = {0,0,0,0}, pW0 = {0,0,0,0}, pW1 = {0,0,0,0};

    auto prefetch = [&](int c) {
        const bool isEmb = c >= 28;
        if (tid < 96) {
            if (am < 22)
                pA = isEmb ? *(const float4*)&emb[am * 64 + (c - 28) * 16 + aq * 4]
                           : *(const float4*)&xb[am * kF + c * 16 + aq * 4];
            else
                pA = float4{0,0,0,0};
        }
        #pragma unroll
        for (int t = 0; t < 2; ++t) {
            const int idx = tid + t * 512;
            const int k = idx >> 6, qq = idx & 63;
            const int s = qq >> 4, cq = qq & 15;
            float4 v = {0,0,0,0};
            if (!isEmb) {
                const float* src =
                    (s == 0) ? &cw1[(size_t)(c * 16 + k) * 64] :
                    (s == 1) ? &cw1[(size_t)(448 + c * 16 + k) * 64] :
                    (s == 2) ? &sw1[(size_t)(128 + c * 16 + k) * 64] :
                               &sw1[(size_t)(576 + c * 16 + k) * 64];
                v = *(const float4*)&src[cq * 4];
            } else if (s >= 2) {
                v = *(const float4*)&sw1[(size_t)((s - 2) * 64 + (c - 28) * 16 + k) * 64 + cq * 4];
            }
            if (t == 0) pW0 = v; else pW1 = v;
        }
    };
    auto commit = [&](int c, int buf) {
        const bool isEmb = c >= 28;
        if (tid < 96) {
            float* at = sm + oAT + buf * kATb;
            at[(aq * 4 + 0) * 26 + am] = pA.x;
            at[(aq * 4 + 1) * 26 + am] = pA.y;
            at[(aq * 4 + 2) * 26 + am] = pA.z;
            at[(aq * 4 + 3) * 26 + am] = pA.w;
        }
        #pragma unroll
        for (int t = 0; t < 2; ++t) {
            const int idx = tid + t * 512;
            const int k = idx >> 6, qq = idx & 63;
            const int s = qq >> 4;
            if (!isEmb || s >= 2)
                *(float4*)&sm[oW + buf * kWb + k * kWStr + qq * 4] = (t == 0) ? pW0 : pW1;
        }
    };
    auto compute = [&](int c, int buf) {
        const bool isEmb = c >= 28;
        if (isEmb && g < 2) return;    // emb K only touches cols 128..255 (wave-uniform skip)
        const float* at = sm + oAT + buf * kATb;
        const float* wp = sm + oW + buf * kWb;
        #pragma unroll
        for (int k = 0; k < 16; ++k) {
            const float a0 = at[k * 26 + r0];
            const float a1 = at[k * 26 + r0 + 1];
            const float a2 = at[k * 26 + r0 + 2];
            const float4 w4 = *(const float4*)&wp[k * kWStr + col];
            acc0.x = fmaf(a0, w4.x, acc0.x); acc0.y = fmaf(a0, w4.y, acc0.y);
            acc0.z = fmaf(a0, w4.z, acc0.z); acc0.w = fmaf(a0, w4.w, acc0.w);
            acc1.x = fmaf(a1, w4.x, acc1.x); acc1.y = fmaf(a1, w4.y, acc1.y);
            acc1.z = fmaf(a1, w4.z, acc1.z); acc1.w = fmaf(a1, w4.w, acc1.w);
            acc2.x = fmaf(a2, w4.x, acc2.x); acc2.y = fmaf(a2, w4.y, acc2.y);
            acc2.z = fmaf(a2, w4.z, acc2.z); acc2.w = fmaf(a2, w4.w, acc2.w);
        }
    };

    prefetch(0);
    commit(0, 0);
    __syncthreads();
    for (int c = 0; c < 32; ++c) {
        if (c < 31) prefetch(c + 1);
        compute(c, c & 1);
        if (c < 31) commit(c + 1, (c + 1) & 1);
        __syncthreads();
    }

    // P store (+bias fold: a1 += cb1, u1 += sb1)
    {
        float4 bias = {0,0,0,0};
        if (g == 0)      bias = *(const float4*)&cb1[q16 * 4];
        else if (g == 2) bias = *(const float4*)&sb1[q16 * 4];
        const float4 av[3] = {acc0, acc1, acc2};
        #pragma unroll
        for (int r = 0; r < 3; ++r) {
            const int row = r0 + r;
            if (row < 22) {
                float4 o;
                o.x = av[r].x + bias.x; o.y = av[r].y + bias.y;
                o.z = av[r].z + bias.z; o.w = av[r].w + bias.w;
                *(float4*)&sm[oP + row * kPStr + col] = o;
            }
        }
    }
    // stage small consts into region X (GEMM staging is dead)
    if (tid < 64)       { sm[oCst + tid] = cw2[tid]; sm[oCst + 64 + tid] = ln_g[tid]; sm[oCst + 128 + tid] = ln_b[tid]; }
    else if (tid < 96)  { sm[oCst + 192 + tid - 64] = sw3[tid - 64]; }
    else if (tid < 128) { sm[oCst + 224 + tid - 96] = sb2[tid - 96]; }
    __syncthreads();

    // ================= phase 3: pair weights, 2 chunks of 128 slots =========
    const float* scw2 = sm + oCst;
    const float* slng = sm + oCst + 64;
    const float* slnb = sm + oCst + 128;
    const float* ssw3 = sm + oCst + 192;
    const float* ssb2 = sm + oCst + 224;

    for (int ch = 0; ch < 2; ++ch) {
        // --- sub1: LN+relu V-build (4 lanes/slot) + dual corr-weight dots ---
        {
            const int sl = tid >> 2, t4 = tid & 3;
            int s = ch * 128 + sl; if (s > 252) s = 252;
            int i, j; map_slot(s, i, j);
            const float* u1 = sm + oP + i * kPStr + 128 + t4 * 16;
            const float* u2 = sm + oP + j * kPStr + 192 + t4 * 16;
            float raw[16]; float s1 = 0.f;
            #pragma unroll
            for (int c4 = 0; c4 < 4; ++c4) {
                const float4 a = *(const float4*)&u1[c4 * 4];
                const float4 e = *(const float4*)&u2[c4 * 4];
                raw[c4*4+0] = a.x + e.x; raw[c4*4+1] = a.y + e.y;
                raw[c4*4+2] = a.z + e.z; raw[c4*4+3] = a.w + e.w;
                s1 += raw[c4*4+0] + raw[c4*4+1] + raw[c4*4+2] + raw[c4*4+3];
            }
            s1 += __shfl_xor(s1, 1, 64); s1 += __shfl_xor(s1, 2, 64);
            const float mean = s1 * (1.f / 64.f);
            float s2 = 0.f;
            #pragma unroll
            for (int c = 0; c < 16; ++c) { const float d = raw[c] - mean; s2 = fmaf(d, d, s2); }
            s2 += __shfl_xor(s2, 1, 64); s2 += __shfl_xor(s2, 2, 64);
            const float rstd = rsqrtf(s2 * (1.f / 64.f) + 1e-5f);
            float* vbp = sm + oVB + sl * kVStr + t4 * 16;
            #pragma unroll
            for (int c = 0; c < 16; ++c) {
                const int k = t4 * 16 + c;
                vbp[c] = fmaxf(fmaf((raw[c] - mean) * rstd, slng[k], slnb[k]), 0.f);
            }
            // dual corr-weight partial dots
            const float* a1i = sm + oP + i * kPStr + t4 * 16;
            const float* a2j = sm + oP + j * kPStr + 64 + t4 * 16;
            const float* a1j = sm + oP + j * kPStr + t4 * 16;
            const float* a2i = sm + oP + i * kPStr + 64 + t4 * 16;
            float zc1 = 0.f, zc2 = 0.f;
            #pragma unroll
            for (int c = 0; c < 16; ++c) {
                const float wv = scw2[t4 * 16 + c];
                zc1 = fmaf(fmaxf(a1i[c] + a2j[c], 0.f), wv, zc1);
                zc2 = fmaf(fmaxf(a1j[c] + a2i[c], 0.f), wv, zc2);
            }
            zc1 += __shfl_xor(zc1, 1, 64); zc1 += __shfl_xor(zc1, 2, 64);
            zc2 += __shfl_xor(zc2, 1, 64); zc2 += __shfl_xor(zc2, 2, 64);
            if (t4 == 0) { sm[oZC + sl * 2] = zc1; sm[oZC + sl * 2 + 1] = zc2; }
        }
        __syncthreads();
        // --- sub2: V(128x64) @ sw2(64x32) GEMM + layer-3 + finalize ---
        {
            const int w = tid >> 6, l = tid & 63;
            const int cq = l & 7, sg2 = l >> 3;
            const int sl0 = w * 16 + sg2 * 2, sl1 = sl0 + 1;
            const float* vb0 = sm + oVB + sl0 * kVStr;
            const float* vb1 = sm + oVB + sl1 * kVStr;
            float4 aA = {0,0,0,0}, aB = {0,0,0,0};
            #pragma unroll 4
            for (int k = 0; k < 64; ++k) {
                const float4 w4 = *(const float4*)&sw2[k * 32 + cq * 4];  // L2-resident
                const float va = vb0[k], ve = vb1[k];
                aA.x = fmaf(va, w4.x, aA.x); aA.y = fmaf(va, w4.y, aA.y);
                aA.z = fmaf(va, w4.z, aA.z); aA.w = fmaf(va, w4.w, aA.w);
                aB.x = fmaf(ve, w4.x, aB.x); aB.y = fmaf(ve, w4.y, aB.y);
                aB.z = fmaf(ve, w4.z, aB.z); aB.w = fmaf(ve, w4.w, aB.w);
            }
            const int o0 = cq * 4;
            float zA, zB;
            zA  = fmaxf(aA.x + ssb2[o0+0], 0.f) * ssw3[o0+0];
            zA += fmaxf(aA.y + ssb2[o0+1], 0.f) * ssw3[o0+1];
            zA += fmaxf(aA.z + ssb2[o0+2], 0.f) * ssw3[o0+2];
            zA += fmaxf(aA.w + ssb2[o0+3], 0.f) * ssw3[o0+3];
            zB  = fmaxf(aB.x + ssb2[o0+0], 0.f) * ssw3[o0+0];
            zB += fmaxf(aB.y + ssb2[o0+1], 0.f) * ssw3[o0+1];
            zB += fmaxf(aB.z + ssb2[o0+2], 0.f) * ssw3[o0+2];
            zB += fmaxf(aB.w + ssb2[o0+3], 0.f) * ssw3[o0+3];
            zA += __shfl_xor(zA, 1, 64); zA += __shfl_xor(zA, 2, 64); zA += __shfl_xor(zA, 4, 64);
            zB += __shfl_xor(zB, 1, 64); zB += __shfl_xor(zB, 2, 64); zB += __shfl_xor(zB, 4, 64);
            if (cq == 0) {
                const float alpha = 1.f / (1.f + __expf(-alpha_p[0]));
                const float cb2s  = cb2[0];
                #pragma unroll
                for (int e = 0; e < 2; ++e) {
                    const int sl = e ? sl1 : sl0;
                    const float z = e ? zB : zA;
                    const int s = ch * 128 + sl;
                    if (s < 253) {
                        int i, j; map_slot(s, i, j);
                        const float zc1 = sm[oZC + sl * 2];
                        const float zc2 = sm[oZC + sl * 2 + 1];
                        const float wc1 = 1.f / (1.f + __expf(-(zc1 + cb2s)));
                        float gsem;
                        if (i == j) {
                            gsem = 1.f;
                        } else {
                            // accurate expf: feeds a hard threshold compare
                            const float wsem = 1.f / (1.f + expf(-(z + sb3[0])));
                            const float tt   = 1.f / (1.f + expf(-thr[0]));
                            gsem = (wsem > tt) ? wsem : 0.f;
                        }
                        const float gc1 = fmaf(sm[oSG + i * 22 + j], wc1, (i == j) ? 1.f : 0.f);
                        out[(size_t)b * kNP + i * 22 + j] = fmaf(alpha, gc1, (1.f - alpha) * gsem);
                        if (i != j) {
                            const float wc2 = 1.f / (1.f + __expf(-(zc2 + cb2s)));
                            const float gc2 = sm[oSG + j * 22 + i] * wc2;
                            out[(size_t)b * kNP + j * 22 + i] = fmaf(alpha, gc2, (1.f - alpha) * gsem);
                        }
                    }
                }
            }
        }
        __syncthreads();   // vbuf/zc reuse next chunk
    }
}

extern "C" void kernel_launch(void* const* d_in, const int* in_sizes, int n_in,
                              void* d_out, int out_size, void* d_ws, size_t ws_size,
                              hipStream_t stream)
{
    (void)n_in; (void)out_size; (void)d_ws; (void)ws_size;
    const float* x     = (const float*)d_in[0];
    const float* cw1   = (const float*)d_in[1];
    const float* cb1   = (const float*)d_in[2];
    const float* cw2   = (const float*)d_in[3];
    const float* cb2   = (const float*)d_in[4];
    const float* emb   = (const float*)d_in[5];
    const float* sw1   = (const float*)d_in[6];
    const float* sb1   = (const float*)d_in[7];
    const float* ln_g  = (const float*)d_in[8];
    const float* ln_b  = (const float*)d_in[9];
    const float* sw2   = (const float*)d_in[10];
    const float* sb2   = (const float*)d_in[11];
    const float* sw3   = (const float*)d_in[12];
    const float* sb3   = (const float*)d_in[13];
    const float* thr   = (const float*)d_in[14];
    const float* alpha = (const float*)d_in[15];
    float* out = (float*)d_out;

    const int B = in_sizes[0] / (kN * kF);
    hipLaunchKernelGGL(hgc_fused, dim3(B), dim3(512), 0, stream,
                       x, cw1, cb1, cw2, cb2, emb, sw1, sb1, ln_g, ln_b,
                       sw2, sb2, sw3, sb3, thr, alpha, out);
}

// Round 6
// 126.754 us; speedup vs baseline: 1.1710x; 1.1710x over previous
//
#include <hip/hip_runtime.h>
#include <math.h>

namespace {
constexpr int kN = 22;
constexpr int kF = 448;
constexpr int kNP = 484;
// kernel1 shared pool (floats): corr role needs 22*452 + 44 = 9988 (39.95 KB)
constexpr int kXStr = 452;                  // 16B-aligned rows, 452%32==4 bank spread
constexpr int kSm1 = kN * kXStr + 2 * kN;   // 9988
// GEMM overlays (union with corr pool): As[64][36]=2304 + Bs[64][68]=4352
constexpr int kAStr = 36;
constexpr int kBStr = 68;
// kernel2
constexpr int kPStr = 68;
constexpr int kVStr = 68;

__device__ __forceinline__ void map_slot(int s, int& i, int& j) {
    // s<231: strict upper (i<j); else diagonal
    if (s < 231) {
        int rem = s, i0 = 0;
        while (rem >= 21 - i0) { rem -= 21 - i0; ++i0; }
        i = i0; j = i0 + 1 + rem;
    } else {
        i = j = s - 231;
    }
}
}

// =================== kernel 1: projections GEMM + corr ======================
// blocks [0, nGemm): 32x64 SGEMM tiles (2x4 microtile) with register prefetch
//   C = A(M,448) @ W(448,256); col tiles: 0:a1(+cb1) 1:a2 2:u1(+emb@sw1[0:64],+sb1)
//   3:u2(+emb@sw1[64:128])
// blocks [nGemm, nGemm+2B): per-(b,half) corr stats + |corr| rows
__global__ __launch_bounds__(256) void hgc_k1(
    const float* __restrict__ x,
    const float* __restrict__ cw1, const float* __restrict__ cb1,
    const float* __restrict__ emb,
    const float* __restrict__ sw1, const float* __restrict__ sb1,
    float* __restrict__ C, float* __restrict__ g,
    int M, int Mtiles, int nGemm)
{
    __shared__ __align__(16) float sm[kSm1];
    const int tid = threadIdx.x;

    if ((int)blockIdx.x < nGemm) {
        // ---------------- GEMM role ----------------
        float* As = sm;                 // As[k][m], [64][kAStr] (transposed)
        float* Bs = sm + 64 * kAStr;    // Bs[k][n], [64][kBStr]
        const int bm = blockIdx.x % Mtiles;
        const int bn = blockIdx.x / Mtiles;        // 0..3
        const int m0 = bm * 32;

        const float* Wsrc =
            (bn == 0) ? cw1 :
            (bn == 1) ? cw1 + 448 * 64 :
            (bn == 2) ? sw1 + 128 * 64 :
                        sw1 + 576 * 64;

        const int tm = tid & 15;        // rows tm*2, tm*2+1
        const int tn = tid >> 4;        // cols tn*4 .. +3
        float acc[2][4];
        #pragma unroll
        for (int i = 0; i < 2; ++i)
            #pragma unroll
            for (int j = 0; j < 4; ++j) acc[i][j] = 0.f;

        float4 rA[2], rB[4];

        auto preMain = [&](int k0) {
            #pragma unroll
            for (int p = 0; p < 2; ++p) {
                const int idx = tid + p * 256;
                const int row = idx >> 4, kq = idx & 15;
                int m = m0 + row; if (m >= M) m = M - 1;
                rA[p] = *(const float4*)&x[(size_t)m * kF + k0 + kq * 4];
            }
            #pragma unroll
            for (int p = 0; p < 4; ++p) {
                const int idx = tid + p * 256;
                const int k = idx >> 4, nq = idx & 15;
                rB[p] = *(const float4*)&Wsrc[(size_t)(k0 + k) * 64 + nq * 4];
            }
        };
        auto preEmb = [&]() {
            const float* W2 = sw1 + (bn == 2 ? 0 : 64) * 64;
            #pragma unroll
            for (int p = 0; p < 2; ++p) {
                const int idx = tid + p * 256;
                const int row = idx >> 4, kq = idx & 15;
                const int r = (m0 + row) % kN;
                rA[p] = *(const float4*)&emb[(size_t)r * 64 + kq * 4];
            }
            #pragma unroll
            for (int p = 0; p < 4; ++p) {
                const int idx = tid + p * 256;
                const int k = idx >> 4, nq = idx & 15;
                rB[p] = *(const float4*)&W2[(size_t)k * 64 + nq * 4];
            }
        };
        auto commit = [&]() {
            #pragma unroll
            for (int p = 0; p < 2; ++p) {
                const int idx = tid + p * 256;
                const int row = idx >> 4, kq = idx & 15;
                As[(kq * 4 + 0) * kAStr + row] = rA[p].x;
                As[(kq * 4 + 1) * kAStr + row] = rA[p].y;
                As[(kq * 4 + 2) * kAStr + row] = rA[p].z;
                As[(kq * 4 + 3) * kAStr + row] = rA[p].w;
            }
            #pragma unroll
            for (int p = 0; p < 4; ++p) {
                const int idx = tid + p * 256;
                const int k = idx >> 4, nq = idx & 15;
                *(float4*)&Bs[k * kBStr + nq * 4] = rB[p];
            }
        };
        auto compute = [&]() {
            #pragma unroll 8
            for (int k = 0; k < 64; ++k) {
                const float2 a2 = *(const float2*)&As[k * kAStr + tm * 2];
                const float4 b4 = *(const float4*)&Bs[k * kBStr + tn * 4];
                acc[0][0] = fmaf(a2.x, b4.x, acc[0][0]);
                acc[0][1] = fmaf(a2.x, b4.y, acc[0][1]);
                acc[0][2] = fmaf(a2.x, b4.z, acc[0][2]);
                acc[0][3] = fmaf(a2.x, b4.w, acc[0][3]);
                acc[1][0] = fmaf(a2.y, b4.x, acc[1][0]);
                acc[1][1] = fmaf(a2.y, b4.y, acc[1][1]);
                acc[1][2] = fmaf(a2.y, b4.z, acc[1][2]);
                acc[1][3] = fmaf(a2.y, b4.w, acc[1][3]);
            }
        };

        preMain(0);
        commit();
        __syncthreads();
        for (int c = 0; c < 7; ++c) {
            if (c < 6) preMain((c + 1) * 64);        // loads in flight during compute
            else if (bn >= 2) preEmb();
            compute();
            __syncthreads();
            if (c < 6 || bn >= 2) {
                commit();
                __syncthreads();
            }
        }
        if (bn >= 2) compute();                      // emb epilogue chunk

        float4 bias = {0, 0, 0, 0};
        if (bn == 0)      bias = *(const float4*)&cb1[tn * 4];
        else if (bn == 2) bias = *(const float4*)&sb1[tn * 4];
        #pragma unroll
        for (int i = 0; i < 2; ++i) {
            const int m = m0 + tm * 2 + i;
            if (m < M) {
                float4 o;
                o.x = acc[i][0] + bias.x; o.y = acc[i][1] + bias.y;
                o.z = acc[i][2] + bias.z; o.w = acc[i][3] + bias.w;
                *(float4*)&C[(size_t)m * 256 + bn * 64 + tn * 4] = o;
            }
        }
    } else {
        // ---------------- corr role: 2 blocks/b, 11 rows each ----------------
        float* smu = sm + kN * kXStr;
        float* sis = smu + kN;
        const int cb = blockIdx.x - nGemm;
        const int b = cb >> 1;
        const int r0 = (cb & 1) * 11;

        const float4* xb4 = (const float4*)(x + (size_t)b * (kN * kF));
        for (int idx = tid; idx < kN * kF / 4; idx += 256) {
            const float4 v = xb4[idx];
            const int r = idx / 112;
            const int k = (idx - r * 112) * 4;
            float* d = sm + r * kXStr + k;
            d[0] = v.x; d[1] = v.y; d[2] = v.z; d[3] = v.w;
        }
        __syncthreads();

        {
            const int wid = tid >> 6, lane = tid & 63;
            for (int r = wid; r < kN; r += 4) {
                const float* row = sm + r * kXStr;
                float s = 0.f;
                #pragma unroll
                for (int c = 0; c < 7; ++c) s += row[c * 64 + lane];
                #pragma unroll
                for (int o = 32; o; o >>= 1) s += __shfl_xor(s, o, 64);
                const float mean = s * (1.f / 448.f);
                float ss = 0.f;
                #pragma unroll
                for (int c = 0; c < 7; ++c) { const float d = row[c * 64 + lane] - mean; ss = fmaf(d, d, ss); }
                #pragma unroll
                for (int o = 32; o; o >>= 1) ss += __shfl_xor(ss, o, 64);
                if (lane == 0) {
                    smu[r] = mean;
                    sis[r] = 1.f / (sqrtf(ss * (1.f / 447.f)) + 1e-8f);   // ddof=1
                }
            }
        }
        __syncthreads();

        for (int p = tid; p < 11 * kN; p += 256) {
            const int pi = p / 22;
            const int i = r0 + pi, j = p - pi * 22;
            const float4* ri = (const float4*)(sm + i * kXStr);
            const float4* rj = (const float4*)(sm + j * kXStr);
            float dot = 0.f;
            for (int q = 0; q < 112; ++q) {
                const float4 a = ri[q], bq = rj[q];
                dot = fmaf(a.x, bq.x, dot); dot = fmaf(a.y, bq.y, dot);
                dot = fmaf(a.z, bq.z, dot); dot = fmaf(a.w, bq.w, dot);
            }
            const float c = (dot - 448.f * smu[i] * smu[j]) * sis[i] * sis[j] * (1.f / 448.f);
            g[(size_t)b * kNP + i * 22 + j] = fabsf(c);
        }
    }
}

// ===== kernel 2: 4 blocks/b, 64 unique slots each (231 upper + 22 diag) =====
__global__ __launch_bounds__(256) void hgc_k2(
    const float* __restrict__ C, const float* __restrict__ g,
    const float* __restrict__ cw2, const float* __restrict__ cb2,
    const float* __restrict__ sw2, const float* __restrict__ sb2,
    const float* __restrict__ sw3, const float* __restrict__ sb3,
    const float* __restrict__ ln_g, const float* __restrict__ ln_b,
    const float* __restrict__ thr, const float* __restrict__ alpha_p,
    float* __restrict__ out)
{
    __shared__ __align__(16) float sp[4 * kN * kPStr];   // a1|a2|u1|u2
    __shared__ float sg[kNP];
    __shared__ __align__(16) float sw2s[2048];
    __shared__ float scw2[64], slng[64], slnb[64], ssw3[32], ssb2[32];
    __shared__ __align__(16) float vbuf[32 * kVStr];

    const int tid = threadIdx.x;
    const int b   = blockIdx.x >> 2;
    const int pb  = blockIdx.x & 3;

    #pragma unroll
    for (int a = 0; a < 4; ++a) {
        float* dst = sp + a * kN * kPStr;
        for (int idx = tid; idx < 352; idx += 256) {
            const int r = idx >> 4, kq = idx & 15;
            const float4 v = *(const float4*)&C[((size_t)(b * 22 + r)) * 256 + a * 64 + kq * 4];
            *(float4*)&dst[r * kPStr + kq * 4] = v;
        }
    }
    for (int idx = tid; idx < kNP; idx += 256) sg[idx] = g[(size_t)b * kNP + idx];
    {
        const float4* s4 = (const float4*)sw2;
        for (int idx = tid; idx < 512; idx += 256)
            *((float4*)(sw2s + idx * 4)) = s4[idx];
    }
    if (tid < 64)       { scw2[tid] = cw2[tid]; slng[tid] = ln_g[tid]; slnb[tid] = ln_b[tid]; }
    else if (tid < 96)  { ssw3[tid - 64] = sw3[tid - 64]; }
    else if (tid < 128) { ssb2[tid - 96] = sb2[tid - 96]; }
    __syncthreads();

    const int pl = tid >> 3;             // local slot 0..31
    const int t  = tid & 7;
    const float* sa1 = sp;
    const float* sa2 = sp + kN * kPStr;
    const float* su1 = sp + 2 * kN * kPStr;
    const float* su2 = sp + 3 * kN * kPStr;

    for (int ch = 0; ch < 2; ++ch) {
        const int s_ = pb * 64 + ch * 32 + pl;     // 0..255
        const bool valid = s_ < 253;
        const int s = valid ? s_ : 252;
        int i, j; map_slot(s, i, j);

        // w_corr for (i,j) AND (j,i): sigmoid(relu(a1_r + a2_c) . cw2 + cb2)
        float zc1 = 0.f, zc2 = 0.f;
        {
            const float* a1i = sa1 + i * kPStr + t * 8;
            const float* a2j = sa2 + j * kPStr + t * 8;
            const float* a1j = sa1 + j * kPStr + t * 8;
            const float* a2i = sa2 + i * kPStr + t * 8;
            const float4 i0 = *(const float4*)a1i, i1 = *(const float4*)(a1i + 4);
            const float4 j0 = *(const float4*)a2j, j1 = *(const float4*)(a2j + 4);
            const float4 k0 = *(const float4*)a1j, k1 = *(const float4*)(a1j + 4);
            const float4 l0 = *(const float4*)a2i, l1 = *(const float4*)(a2i + 4);
            const float4 w0 = *(const float4*)(scw2 + t * 8);
            const float4 w1 = *(const float4*)(scw2 + t * 8 + 4);
            zc1 = fmaf(fmaxf(i0.x + j0.x, 0.f), w0.x, zc1);
            zc1 = fmaf(fmaxf(i0.y + j0.y, 0.f), w0.y, zc1);
            zc1 = fmaf(fmaxf(i0.z + j0.z, 0.f), w0.z, zc1);
            zc1 = fmaf(fmaxf(i0.w + j0.w, 0.f), w0.w, zc1);
            zc1 = fmaf(fmaxf(i1.x + j1.x, 0.f), w1.x, zc1);
            zc1 = fmaf(fmaxf(i1.y + j1.y, 0.f), w1.y, zc1);
            zc1 = fmaf(fmaxf(i1.z + j1.z, 0.f), w1.z, zc1);
            zc1 = fmaf(fmaxf(i1.w + j1.w, 0.f), w1.w, zc1);
            zc2 = fmaf(fmaxf(k0.x + l0.x, 0.f), w0.x, zc2);
            zc2 = fmaf(fmaxf(k0.y + l0.y, 0.f), w0.y, zc2);
            zc2 = fmaf(fmaxf(k0.z + l0.z, 0.f), w0.z, zc2);
            zc2 = fmaf(fmaxf(k0.w + l0.w, 0.f), w0.w, zc2);
            zc2 = fmaf(fmaxf(k1.x + l1.x, 0.f), w1.x, zc2);
            zc2 = fmaf(fmaxf(k1.y + l1.y, 0.f), w1.y, zc2);
            zc2 = fmaf(fmaxf(k1.z + l1.z, 0.f), w1.z, zc2);
            zc2 = fmaf(fmaxf(k1.w + l1.w, 0.f), w1.w, zc2);
            zc1 += __shfl_xor(zc1, 1, 64); zc1 += __shfl_xor(zc1, 2, 64); zc1 += __shfl_xor(zc1, 4, 64);
            zc2 += __shfl_xor(zc2, 1, 64); zc2 += __shfl_xor(zc2, 2, 64); zc2 += __shfl_xor(zc2, 4, 64);
        }

        // semantic for (i,j) with i<=j
        float raw[8];
        float s1 = 0.f;
        {
            const float* pu1 = su1 + i * kPStr + t * 8;
            const float* pu2 = su2 + j * kPStr + t * 8;
            const float4 u0 = *(const float4*)pu1, u1v = *(const float4*)(pu1 + 4);
            const float4 v0 = *(const float4*)pu2, v1v = *(const float4*)(pu2 + 4);
            raw[0] = u0.x + v0.x; raw[1] = u0.y + v0.y; raw[2] = u0.z + v0.z; raw[3] = u0.w + v0.w;
            raw[4] = u1v.x + v1v.x; raw[5] = u1v.y + v1v.y; raw[6] = u1v.z + v1v.z; raw[7] = u1v.w + v1v.w;
            #pragma unroll
            for (int c = 0; c < 8; ++c) s1 += raw[c];
        }
        s1 += __shfl_xor(s1, 1, 64); s1 += __shfl_xor(s1, 2, 64); s1 += __shfl_xor(s1, 4, 64);
        const float mean = s1 * (1.f / 64.f);
        float s2 = 0.f;
        #pragma unroll
        for (int c = 0; c < 8; ++c) { const float d = raw[c] - mean; s2 = fmaf(d, d, s2); }
        s2 += __shfl_xor(s2, 1, 64); s2 += __shfl_xor(s2, 2, 64); s2 += __shfl_xor(s2, 4, 64);
        const float rstd = rsqrtf(s2 * (1.f / 64.f) + 1e-5f);
        {
            float* vb = vbuf + pl * kVStr + t * 8;
            float4 o0, o1;
            o0.x = fmaxf(fmaf((raw[0] - mean) * rstd, slng[t*8+0], slnb[t*8+0]), 0.f);
            o0.y = fmaxf(fmaf((raw[1] - mean) * rstd, slng[t*8+1], slnb[t*8+1]), 0.f);
            o0.z = fmaxf(fmaf((raw[2] - mean) * rstd, slng[t*8+2], slnb[t*8+2]), 0.f);
            o0.w = fmaxf(fmaf((raw[3] - mean) * rstd, slng[t*8+3], slnb[t*8+3]), 0.f);
            o1.x = fmaxf(fmaf((raw[4] - mean) * rstd, slng[t*8+4], slnb[t*8+4]), 0.f);
            o1.y = fmaxf(fmaf((raw[5] - mean) * rstd, slng[t*8+5], slnb[t*8+5]), 0.f);
            o1.z = fmaxf(fmaf((raw[6] - mean) * rstd, slng[t*8+6], slnb[t*8+6]), 0.f);
            o1.w = fmaxf(fmaf((raw[7] - mean) * rstd, slng[t*8+7], slnb[t*8+7]), 0.f);
            *(float4*)vb = o0;
            *(float4*)(vb + 4) = o1;
        }
        __syncthreads();

        // 64x32 GEMV: lane owns outputs t*4 .. t*4+3
        float4 acc = {0, 0, 0, 0};
        {
            const float* vb = vbuf + pl * kVStr;
            for (int k = 0; k < 64; ++k) {
                const float v = vb[k];
                const float4 w = *((const float4*)(sw2s + k * 32 + t * 4));
                acc.x = fmaf(v, w.x, acc.x); acc.y = fmaf(v, w.y, acc.y);
                acc.z = fmaf(v, w.z, acc.z); acc.w = fmaf(v, w.w, acc.w);
            }
        }
        float z2;
        {
            const int o0 = t * 4;
            z2  = fmaxf(acc.x + ssb2[o0 + 0], 0.f) * ssw3[o0 + 0];
            z2 += fmaxf(acc.y + ssb2[o0 + 1], 0.f) * ssw3[o0 + 1];
            z2 += fmaxf(acc.z + ssb2[o0 + 2], 0.f) * ssw3[o0 + 2];
            z2 += fmaxf(acc.w + ssb2[o0 + 3], 0.f) * ssw3[o0 + 3];
            z2 += __shfl_xor(z2, 1, 64); z2 += __shfl_xor(z2, 2, 64); z2 += __shfl_xor(z2, 4, 64);
        }

        if (valid && t == 0) {
            const float alpha = 1.f / (1.f + __expf(-alpha_p[0]));
            const float wc1 = 1.f / (1.f + __expf(-(zc1 + cb2[0])));
            float gsem;
            if (i == j) {
                gsem = 1.f;
            } else {
                // accurate expf: this sigmoid feeds a hard threshold compare
                const float wsem = 1.f / (1.f + expf(-(z2 + sb3[0])));
                const float tt   = 1.f / (1.f + expf(-thr[0]));
                gsem = (wsem > tt) ? wsem : 0.f;
            }
            const float gc1 = fmaf(sg[i * 22 + j], wc1, (i == j) ? 1.f : 0.f);
            out[(size_t)b * kNP + i * 22 + j] = fmaf(alpha, gc1, (1.f - alpha) * gsem);
            if (i != j) {
                const float wc2 = 1.f / (1.f + __expf(-(zc2 + cb2[0])));
                const float gc2 = sg[j * 22 + i] * wc2;
                out[(size_t)b * kNP + j * 22 + i] = fmaf(alpha, gc2, (1.f - alpha) * gsem);
            }
        }
        __syncthreads();   // vbuf reuse across chunks
    }
}

extern "C" void kernel_launch(void* const* d_in, const int* in_sizes, int n_in,
                              void* d_out, int out_size, void* d_ws, size_t ws_size,
                              hipStream_t stream)
{
    (void)n_in; (void)out_size; (void)ws_size;
    const float* x     = (const float*)d_in[0];
    const float* cw1   = (const float*)d_in[1];
    const float* cb1   = (const float*)d_in[2];
    const float* cw2   = (const float*)d_in[3];
    const float* cb2   = (const float*)d_in[4];
    const float* emb   = (const float*)d_in[5];
    const float* sw1   = (const float*)d_in[6];
    const float* sb1   = (const float*)d_in[7];
    const float* ln_g  = (const float*)d_in[8];
    const float* ln_b  = (const float*)d_in[9];
    const float* sw2   = (const float*)d_in[10];
    const float* sb2   = (const float*)d_in[11];
    const float* sw3   = (const float*)d_in[12];
    const float* sb3   = (const float*)d_in[13];
    const float* thr   = (const float*)d_in[14];
    const float* alpha = (const float*)d_in[15];
    float* out = (float*)d_out;
    float* ws  = (float*)d_ws;

    const int B = in_sizes[0] / (kN * kF);
    const int M = kN * B;
    const int Mtiles = (M + 31) / 32;
    const int nGemm = Mtiles * 4;

    float* C = ws;                           // M x 256
    float* g = ws + (size_t)M * 256;         // B x 484

    hipLaunchKernelGGL(hgc_k1, dim3(nGemm + 2 * B), dim3(256), 0, stream,
                       x, cw1, cb1, emb, sw1, sb1, C, g, M, Mtiles, nGemm);
    hipLaunchKernelGGL(hgc_k2, dim3(4 * B), dim3(256), 0, stream,
                       C, g, cw2, cb2, sw2, sb2, sw3, sb3, ln_g, ln_b, thr, alpha, out);
}